// Round 3
// baseline (1407.213 us; speedup 1.0000x reference)
//
#include <hip/hip_runtime.h>
#include <stdint.h>
#include <stddef.h>

#define Bn    16
#define Nn    10000
#define En    320000
#define CIN   32
#define COUTn 64
#define CCn   96
#define WROWU 768           // uints per full node row (16 batches * 96ch / 2)
#define RHU   512           // uints per rh-only node row (16 * 64 / 2)
#define MROWS 160000        // Nn * Bn

typedef __attribute__((ext_vector_type(8))) short short8;   // 8 bf16 = 4 VGPRs
typedef __attribute__((ext_vector_type(4))) float f32x4;
typedef __attribute__((ext_vector_type(2))) unsigned int uint2v;  // nontemporal-safe

// ---------------- bf16 helpers ----------------
__device__ __forceinline__ float bflo(unsigned int p) { return __uint_as_float(p << 16); }
__device__ __forceinline__ float bfhi(unsigned int p) { return __uint_as_float(p & 0xffff0000u); }
__device__ __forceinline__ float bf2f(unsigned short u) { return __uint_as_float(((unsigned int)u) << 16); }
__device__ __forceinline__ unsigned int f2bfbits(float f) {
  unsigned int x = __float_as_uint(f);
  return (x + 0x7fffu + ((x >> 16) & 1u)) >> 16;
}
__device__ __forceinline__ unsigned int pack2(float lo, float hi) {
  return f2bfbits(lo) | (f2bfbits(hi) << 16);
}

// ---------------- edge_index dtype detection ----------------
__global__ void detect_idx(const int* __restrict__ idx, int* __restrict__ flag) {
  if (threadIdx.x == 0 && blockIdx.x == 0) {
    int is64 = 1;
    for (int i = 1; i < 128; i += 2) {
      if (idx[i] != 0) { is64 = 0; break; }
    }
    flag[0] = is64;
  }
}

__device__ __forceinline__ int gidx(const int* __restrict__ p, int i, int is64) {
  return is64 ? p[2 * (long long)i] : p[i];
}

// ---------------- degree + CSR row counts ----------------
__global__ void deg_cnt_kernel(const int* __restrict__ idx, const float* __restrict__ w,
                               float* __restrict__ deg_f, float* __restrict__ deg_b,
                               int* __restrict__ cnt_f, int* __restrict__ cnt_b,
                               const int* __restrict__ flag) {
  int e = blockIdx.x * 256 + threadIdx.x;
  int is64 = flag[0];
  if (e < En) {
    int s = gidx(idx, e, is64);
    int d = gidx(idx, En + e, is64);
    float we = w[e];
    atomicAdd(&deg_f[s], we);
    atomicAdd(&deg_b[d], we);
    atomicAdd(&cnt_f[d], 1);
    atomicAdd(&cnt_b[s], 1);
  }
}

// ---------------- exclusive scan ----------------
__global__ void exscan_two(const int* __restrict__ cnt_f, const int* __restrict__ cnt_b,
                           int* __restrict__ rp_f, int* __restrict__ rp_b,
                           int* __restrict__ cur_f, int* __restrict__ cur_b, int n) {
  const int* cnt = (blockIdx.x == 0) ? cnt_f : cnt_b;
  int* rp  = (blockIdx.x == 0) ? rp_f  : rp_b;
  int* cur = (blockIdx.x == 0) ? cur_f : cur_b;
  __shared__ int sh[256];
  int t = threadIdx.x;
  int running = 0;
  for (int base = 0; base < n; base += 256) {
    int v = (base + t < n) ? cnt[base + t] : 0;
    sh[t] = v;
    __syncthreads();
    for (int off = 1; off < 256; off <<= 1) {
      int x = (t >= off) ? sh[t - off] : 0;
      __syncthreads();
      sh[t] += x;
      __syncthreads();
    }
    int excl = sh[t] - v;
    if (base + t < n) { rp[base + t] = running + excl; cur[base + t] = running + excl; }
    int total = sh[255];
    __syncthreads();
    running += total;
  }
  if (t == 0) rp[n] = running;
}

// ---------------- CSR fill: packed (col, w) uint2 ----------------
__global__ void fill_csr(const int* __restrict__ idx, const float* __restrict__ w,
                         const float* __restrict__ deg_f, const float* __restrict__ deg_b,
                         int* __restrict__ cur_f, int* __restrict__ cur_b,
                         uint2v* __restrict__ cwf, uint2v* __restrict__ cwb,
                         const int* __restrict__ flag) {
  int e = blockIdx.x * 256 + threadIdx.x;
  int is64 = flag[0];
  if (e < En) {
    int s = gidx(idx, e, is64);
    int d = gidx(idx, En + e, is64);
    float we = w[e];
    int pf = atomicAdd(&cur_f[d], 1);
    uint2v ef; ef.x = (unsigned int)s; ef.y = __float_as_uint(we / deg_f[s]);
    cwf[pf] = ef;
    int pb = atomicAdd(&cur_b[s], 1);
    uint2v eb; eb.x = (unsigned int)d; eb.y = __float_as_uint(we / deg_b[d]);
    cwb[pb] = eb;
  }
}

// ---------------- weight prep: transposed bf16, W0 folded (W0-W3-W4) ----------------
__global__ void build_wt(const float* __restrict__ ru_p, const float* __restrict__ c_p,
                         unsigned short* __restrict__ Wt1, unsigned short* __restrict__ Wt2) {
  int i = blockIdx.x * 256 + threadIdx.x;
  if (i < 128 * 480) {
    int n = i / 480, k = i % 480;
    int t = k / 96, kk = k % 96;
    float v;
    if (t == 0) v = ru_p[(kk * 5 + 0) * 128 + n] - ru_p[(kk * 5 + 3) * 128 + n] - ru_p[(kk * 5 + 4) * 128 + n];
    else        v = ru_p[(kk * 5 + t) * 128 + n];
    Wt1[i] = (unsigned short)f2bfbits(v);
  }
  if (i < 64 * 480) {
    int n = i / 480, k = i % 480;
    int t = k / 96, kk = k % 96;
    float v;
    if (t == 0) v = c_p[(kk * 5 + 0) * 64 + n] - c_p[(kk * 5 + 3) * 64 + n] - c_p[(kk * 5 + 4) * 64 + n];
    else        v = c_p[(kk * 5 + t) * 64 + n];
    Wt2[i] = (unsigned short)f2bfbits(v);
  }
}

// ---------------- X0 builder ----------------
__global__ void build_x0_ru(const float* __restrict__ x, const float* __restrict__ h,
                            unsigned int* __restrict__ X0) {
  long long p = (long long)blockIdx.x * 256 + threadIdx.x;
  int node = (int)(p / WROWU);
  int rem = (int)(p % WROWU);
  int b = rem / 48;
  int ci = (rem % 48) * 2;
  float lo, hi;
  if (ci < CIN) {
    const float* s = x + ((size_t)b * Nn + node) * CIN + ci;
    lo = s[0]; hi = s[1];
  } else {
    const float* s = h + ((size_t)b * Nn + node) * COUTn + (ci - CIN);
    lo = s[0]; hi = s[1];
  }
  X0[p] = pack2(lo, hi);
}

// ---------------- XCD-sliced propagation, 2 rows per wave ----------------
// Node rows of RU uints are split into 8 channel slices of 32*UPL uints.
// slice = blockIdx & 7 -> with round-robin WG dispatch each XCD only gathers
// its own Nn*32*UPL*4-byte slice (3.84 MB conv1 / 2.56 MB conv2), L2-resident.
// Each wave: lanes 0-31 own row r, lanes 32-63 own row r+1 (full 64-lane use).
// Main loop runs unmasked to min(len0,len1); short masked tail to max.
// Edge (col,w) loads and output stores are non-temporal (evict-first) so the
// node slice keeps the L2.
template<int RU, int UPL>
__device__ __forceinline__ void prop_row2(const unsigned int* __restrict__ in,
                                          unsigned int* __restrict__ out,
                                          const int* __restrict__ rp,
                                          const uint2v* __restrict__ cw,
                                          int row, int uoff, float alpha) {
  int jb = rp[row];
  int je = rp[row + 1];
  int len = je - jb;
  int lenO = __shfl_xor(len, 32);
  int minl = min(len, lenO);
  int maxl = max(len, lenO);

  float a[2 * UPL];
  #pragma unroll
  for (int k = 0; k < 2 * UPL; ++k) a[k] = 0.f;

  const unsigned int* __restrict__ base = in + uoff;

  int i = 0;
  for (; i + 4 <= minl; i += 4) {
    uint2v e0 = __builtin_nontemporal_load(&cw[jb + i + 0]);
    uint2v e1 = __builtin_nontemporal_load(&cw[jb + i + 1]);
    uint2v e2 = __builtin_nontemporal_load(&cw[jb + i + 2]);
    uint2v e3 = __builtin_nontemporal_load(&cw[jb + i + 3]);
    const unsigned int* p0 = base + (size_t)e0.x * RU;
    const unsigned int* p1 = base + (size_t)e1.x * RU;
    const unsigned int* p2 = base + (size_t)e2.x * RU;
    const unsigned int* p3 = base + (size_t)e3.x * RU;
    unsigned int q0[UPL], q1[UPL], q2[UPL], q3[UPL];
    #pragma unroll
    for (int k = 0; k < UPL; ++k) q0[k] = p0[k];
    #pragma unroll
    for (int k = 0; k < UPL; ++k) q1[k] = p1[k];
    #pragma unroll
    for (int k = 0; k < UPL; ++k) q2[k] = p2[k];
    #pragma unroll
    for (int k = 0; k < UPL; ++k) q3[k] = p3[k];
    float w0 = __uint_as_float(e0.y);
    float w1 = __uint_as_float(e1.y);
    float w2 = __uint_as_float(e2.y);
    float w3 = __uint_as_float(e3.y);
    #pragma unroll
    for (int k = 0; k < UPL; ++k) {
      a[2 * k]     += w0 * bflo(q0[k]);
      a[2 * k + 1] += w0 * bfhi(q0[k]);
      a[2 * k]     += w1 * bflo(q1[k]);
      a[2 * k + 1] += w1 * bfhi(q1[k]);
      a[2 * k]     += w2 * bflo(q2[k]);
      a[2 * k + 1] += w2 * bfhi(q2[k]);
      a[2 * k]     += w3 * bflo(q3[k]);
      a[2 * k + 1] += w3 * bfhi(q3[k]);
    }
  }
  // masked tail (covers min-remainder for both halves + max-min for the longer)
  for (; i < maxl; ++i) {
    bool v = i < len;
    uint2v e = __builtin_nontemporal_load(&cw[jb + (v ? i : 0)]);
    unsigned int col = v ? e.x : 0u;
    float w = v ? __uint_as_float(e.y) : 0.f;
    const unsigned int* p = base + (size_t)col * RU;
    #pragma unroll
    for (int k = 0; k < UPL; ++k) {
      unsigned int q = p[k];
      a[2 * k]     += w * bflo(q);
      a[2 * k + 1] += w * bfhi(q);
    }
  }

  unsigned int* o = out + (size_t)row * RU + uoff;
  #pragma unroll
  for (int k = 0; k < UPL; ++k)
    __builtin_nontemporal_store(pack2(alpha * a[2 * k], alpha * a[2 * k + 1]), &o[k]);
}

template<int RU, int UPL>
__launch_bounds__(256)
__global__ void prop_dual2(const unsigned int* __restrict__ in,
                           unsigned int* __restrict__ outF,
                           unsigned int* __restrict__ outB,
                           const int* __restrict__ rp_f, const uint2v* __restrict__ cwf,
                           const int* __restrict__ rp_b, const uint2v* __restrict__ cwb) {
  int tid = threadIdx.x;
  int wave = tid >> 6;
  int lane = tid & 63;
  int half = lane >> 5;
  int lm = lane & 31;
  int slice = blockIdx.x & 7;
  int row = ((blockIdx.x >> 3) << 3) + wave * 2 + half;
  int uoff = slice * (32 * UPL) + lm * UPL;
  prop_row2<RU, UPL>(in, outF, rp_f, cwf, row, uoff, 1.f);
  prop_row2<RU, UPL>(in, outB, rp_b, cwb, row, uoff, 1.f);
}

template<int RU, int UPL>
__launch_bounds__(256)
__global__ void prop_ck2(const unsigned int* __restrict__ in,
                         unsigned int* __restrict__ out,
                         const int* __restrict__ rp, const uint2v* __restrict__ cw,
                         float alpha) {
  int tid = threadIdx.x;
  int wave = tid >> 6;
  int lane = tid & 63;
  int half = lane >> 5;
  int lm = lane & 31;
  int slice = blockIdx.x & 7;
  int row = ((blockIdx.x >> 3) << 3) + wave * 2 + half;
  int uoff = slice * (32 * UPL) + lm * UPL;
  prop_row2<RU, UPL>(in, out, rp, cw, row, uoff, alpha);
}

// ---------------- MFMA multi-term GEMM ----------------
// C[128 x NT] per block; 4 waves, each 32 x NT. K = nterms*96.
// Weight columns for loop term t are taken at (t0 + t)*96.
// MFMA layouts (verified): A[m=lane&15][k=quad*8+j]; B[k=quad*8+j][n=lane&15];
//                          C/D col=lane&15, row=quad*4+reg.
// MODE 0: conv1 epilogue: v=sigmoid(bias+acc); col<64 -> rh0=v*h (bf16); else U=v (bf16)
// MODE 1: outp = bias + acc (f32, batch-major)
// MODE 2: cp = outp + acc; c=tanh(tanh(cp)); u from U_in; outp = u*h + (1-u)*c
struct Msrc {
  const uint4* xs[5];
  const uint4* rh[5];
};

template<int NT, int MODE>
__launch_bounds__(256)
__global__ void gemm_mfma(Msrc g, int nterms, int t0,
                          const unsigned short* __restrict__ Wt,
                          const float* __restrict__ bias,
                          float* __restrict__ outp,
                          unsigned short* __restrict__ rh0_s,
                          unsigned short* __restrict__ U_out,
                          const unsigned short* __restrict__ U_in,
                          const float* __restrict__ hglob) {
  constexpr int NJ = NT / 16;
  __shared__ __align__(16) unsigned short As[128][104];   // 13 x 16B per row (odd -> conflict-free)
  __shared__ __align__(16) unsigned short Bs[NT][104];

  int m0 = blockIdx.x * 128;
  int tid = threadIdx.x;
  int wave = tid >> 6;
  int lane = tid & 63;
  int quad = lane >> 4;
  int lm = lane & 15;
  int wm = wave * 32;
  int nodeBase = m0 >> 4;

  f32x4 acc[2][NJ];
  #pragma unroll
  for (int i = 0; i < 2; ++i)
    #pragma unroll
    for (int j = 0; j < NJ; ++j) acc[i][j] = (f32x4){0.f, 0.f, 0.f, 0.f};

  for (int t = 0; t < nterms; ++t) {
    const uint4* xs4 = g.xs[t];
    const uint4* rh4 = g.rh[t];
    if (rh4 == nullptr) {
      const uint4* src = xs4 + (size_t)m0 * 12;
      #pragma unroll
      for (int it = 0; it < 6; ++it) {
        int q = tid + it * 256;
        uint4 v = src[q];
        int row = q / 12, slot = q % 12;
        *(uint4*)&As[row][slot * 8] = v;
      }
    } else {
      #pragma unroll
      for (int it = 0; it < 6; ++it) {
        int q = tid + it * 256;
        int row = q / 12, slot = q % 12;
        int node = nodeBase + (row >> 4);
        int b = row & 15;
        uint4 v; int ci0;
        if (slot < 4) { v = xs4[(size_t)node * 192 + b * 12 + slot]; ci0 = slot * 8; }
        else          { v = rh4[(size_t)node * 128 + b * 8 + (slot - 4)]; ci0 = 32 + (slot - 4) * 8; }
        *(uint4*)&As[row][ci0] = v;
      }
    }
    for (int q = tid; q < NT * 12; q += 256) {
      int n = q / 12, slot = q % 12;
      uint4 v = *(const uint4*)(Wt + (size_t)n * 480 + (t0 + t) * 96 + slot * 8);
      *(uint4*)&Bs[n][slot * 8] = v;
    }
    __syncthreads();

    #pragma unroll
    for (int k32 = 0; k32 < 3; ++k32) {
      int kb = k32 * 32 + quad * 8;
      short8 a0 = *(const short8*)&As[wm + lm][kb];
      short8 a1 = *(const short8*)&As[wm + 16 + lm][kb];
      #pragma unroll
      for (int j = 0; j < NJ; ++j) {
        short8 bf = *(const short8*)&Bs[j * 16 + lm][kb];
        acc[0][j] = __builtin_amdgcn_mfma_f32_16x16x32_bf16(a0, bf, acc[0][j], 0, 0, 0);
        acc[1][j] = __builtin_amdgcn_mfma_f32_16x16x32_bf16(a1, bf, acc[1][j], 0, 0, 0);
      }
    }
    __syncthreads();
  }

  #pragma unroll
  for (int i = 0; i < 2; ++i) {
    #pragma unroll
    for (int j = 0; j < NJ; ++j) {
      int col = j * 16 + lm;
      #pragma unroll
      for (int r = 0; r < 4; ++r) {
        int row = m0 + wm + i * 16 + quad * 4 + r;
        int node = row >> 4, b = row & 15;
        float v = acc[i][j][r];
        if (MODE == 0) {
          float s = 1.f / (1.f + expf(-(bias[col] + v)));
          if (col < COUTn) {
            float hv = hglob[((size_t)b * Nn + node) * COUTn + col];
            rh0_s[(size_t)row * 64 + col] = (unsigned short)f2bfbits(s * hv);
          } else {
            U_out[(size_t)row * 64 + (col - COUTn)] = (unsigned short)f2bfbits(s);
          }
        } else if (MODE == 1) {
          outp[((size_t)b * Nn + node) * COUTn + col] = bias[col] + v;
        } else {
          size_t oa = ((size_t)b * Nn + node) * COUTn + col;
          float cp = outp[oa] + v;
          float c = tanhf(tanhf(cp));
          float u = bf2f(U_in[(size_t)row * 64 + col]);
          outp[oa] = u * hglob[oa] + (1.f - u) * c;
        }
      }
    }
  }
}

// ---------------- host ----------------
extern "C" void kernel_launch(void* const* d_in, const int* in_sizes, int n_in,
                              void* d_out, int out_size, void* d_ws, size_t ws_size,
                              hipStream_t stream) {
  const float* x   = (const float*)d_in[0];
  const float* h   = (const float*)d_in[1];
  const int*   idx = (const int*)d_in[2];
  const float* ew  = (const float*)d_in[3];
  const float* ru_param = (const float*)d_in[4];
  const float* ru_bias  = (const float*)d_in[5];
  const float* c_param  = (const float*)d_in[6];
  const float* c_bias   = (const float*)d_in[7];
  float* outp = (float*)d_out;
  (void)in_sizes; (void)n_in; (void)out_size; (void)ws_size;

  char* ws = (char*)d_ws;
  size_t off = 0;
  auto alloc = [&](size_t bytes) -> char* {
    char* p = ws + off;
    off += (bytes + 255) & ~(size_t)255;
    return p;
  };

  float* deg_f = (float*)alloc(40960);
  float* deg_b = (float*)alloc(40960);
  int*   cnt_f = (int*)alloc(40960);
  int*   cnt_b = (int*)alloc(40960);
  int*   rp_f  = (int*)alloc((Nn + 1) * sizeof(int));
  int*   rp_b  = (int*)alloc((Nn + 1) * sizeof(int));
  int*   cur_f = (int*)alloc(Nn * sizeof(int));
  int*   cur_b = (int*)alloc(Nn * sizeof(int));
  int*   flag  = (int*)alloc(256);
  uint2v* cwf  = (uint2v*)alloc((size_t)En * 8);
  uint2v* cwb  = (uint2v*)alloc((size_t)En * 8);
  unsigned short* Wt1 = (unsigned short*)alloc(128 * 480 * 2);
  unsigned short* Wt2 = (unsigned short*)alloc(64 * 480 * 2);

  unsigned int* A0   = (unsigned int*)alloc((size_t)Nn * WROWU * 4);
  unsigned int* T1f  = (unsigned int*)alloc((size_t)Nn * WROWU * 4);
  unsigned int* T1b  = (unsigned int*)alloc((size_t)Nn * WROWU * 4);
  unsigned int* T2f  = (unsigned int*)alloc((size_t)Nn * WROWU * 4);
  unsigned int* T2b  = (unsigned int*)alloc((size_t)Nn * WROWU * 4);
  unsigned int* rh0  = (unsigned int*)alloc((size_t)Nn * RHU * 4);
  unsigned int* rh1f = (unsigned int*)alloc((size_t)Nn * RHU * 4);
  unsigned int* rh1b = (unsigned int*)alloc((size_t)Nn * RHU * 4);
  unsigned int* Ubuf = (unsigned int*)alloc((size_t)Nn * RHU * 4);
  // ~241 MB total

  hipMemsetAsync(ws, 0, 4 * 40960, stream);
  detect_idx<<<1, 64, 0, stream>>>(idx, flag);
  deg_cnt_kernel<<<En / 256, 256, 0, stream>>>(idx, ew, deg_f, deg_b, cnt_f, cnt_b, flag);
  exscan_two<<<2, 256, 0, stream>>>(cnt_f, cnt_b, rp_f, rp_b, cur_f, cur_b, Nn);
  fill_csr<<<En / 256, 256, 0, stream>>>(idx, ew, deg_f, deg_b, cur_f, cur_b,
                                         cwf, cwb, flag);
  build_wt<<<240, 256, 0, stream>>>(ru_param, c_param, Wt1, Wt2);

  const int gBuild = Nn * WROWU / 256;
  const int gP = (Nn / 8) * 8;   // 8 rows/block (2 per wave) x 8 XCD slices

  // ===== conv1 diffusion (rows of 768 uints, slices of 96 uints, 3 uints/lane) =====
  build_x0_ru<<<gBuild, 256, 0, stream>>>(x, h, A0);
  prop_dual2<768, 3><<<gP, 256, 0, stream>>>(A0, T1f, T1b, rp_f, cwf, rp_b, cwb);
  prop_ck2<768, 3><<<gP, 256, 0, stream>>>(T1f, T2f, rp_f, cwf, 2.f);
  prop_ck2<768, 3><<<gP, 256, 0, stream>>>(T1b, T2b, rp_b, cwb, 2.f);

  // ===== conv1 projection: one MFMA GEMM K=480, fused sigmoid + r*h + u-store =====
  Msrc g1;
  g1.xs[0] = (const uint4*)A0;  g1.rh[0] = nullptr;
  g1.xs[1] = (const uint4*)T1f; g1.rh[1] = nullptr;
  g1.xs[2] = (const uint4*)T1b; g1.rh[2] = nullptr;
  g1.xs[3] = (const uint4*)T2f; g1.rh[3] = nullptr;
  g1.xs[4] = (const uint4*)T2b; g1.rh[4] = nullptr;
  gemm_mfma<128, 0><<<MROWS / 128, 256, 0, stream>>>(
      g1, 5, 0, Wt1, ru_bias, nullptr,
      (unsigned short*)rh0, (unsigned short*)Ubuf, nullptr, h);

  // ===== conv2 diffusion on rh (rows of 512 uints, slices of 64 uints, 2 uints/lane) =====
  prop_dual2<512, 2><<<gP, 256, 0, stream>>>(rh0, rh1f, rh1b, rp_f, cwf, rp_b, cwb);

  // conv2 pass A: terms 0,1,2 (weight base t0=0)
  Msrc g2a;
  g2a.xs[0] = (const uint4*)A0;  g2a.rh[0] = (const uint4*)rh0;
  g2a.xs[1] = (const uint4*)T1f; g2a.rh[1] = (const uint4*)rh1f;
  g2a.xs[2] = (const uint4*)T1b; g2a.rh[2] = (const uint4*)rh1b;
  g2a.xs[3] = nullptr; g2a.rh[3] = nullptr;
  g2a.xs[4] = nullptr; g2a.rh[4] = nullptr;
  gemm_mfma<64, 1><<<MROWS / 128, 256, 0, stream>>>(
      g2a, 3, 0, Wt2, c_bias, outp, nullptr, nullptr, nullptr, nullptr);

  // rh second-order terms (reuse rh0/rh1f storage after pass A consumed them)
  prop_ck2<512, 2><<<gP, 256, 0, stream>>>(rh1f, rh0, rp_f, cwf, 2.f);   // rh2f
  prop_ck2<512, 2><<<gP, 256, 0, stream>>>(rh1b, rh1f, rp_b, cwb, 2.f);  // rh2b

  // conv2 pass B: terms 3,4 (weight base t0=3) + fused GRU final
  Msrc g2b;
  g2b.xs[0] = (const uint4*)T2f; g2b.rh[0] = (const uint4*)rh0;
  g2b.xs[1] = (const uint4*)T2b; g2b.rh[1] = (const uint4*)rh1f;
  g2b.xs[2] = nullptr; g2b.rh[2] = nullptr;
  g2b.xs[3] = nullptr; g2b.rh[3] = nullptr;
  g2b.xs[4] = nullptr; g2b.rh[4] = nullptr;
  gemm_mfma<64, 2><<<MROWS / 128, 256, 0, stream>>>(
      g2b, 2, 3, Wt2, c_bias, outp, nullptr, nullptr,
      (const unsigned short*)Ubuf, h);
}

// Round 4
// 1295.592 us; speedup vs baseline: 1.0862x; 1.0862x over previous
//
#include <hip/hip_runtime.h>
#include <stdint.h>
#include <stddef.h>

#define Bn    16
#define Nn    10000
#define En    320000
#define CIN   32
#define COUTn 64
#define CCn   96
#define WROWU 768           // uints per full node row (16 batches * 96ch / 2)
#define RHU   512           // uints per rh-only node row (16 * 64 / 2)
#define MROWS 160000        // Nn * Bn

typedef __attribute__((ext_vector_type(8))) short short8;   // 8 bf16 = 4 VGPRs
typedef __attribute__((ext_vector_type(4))) float f32x4;
typedef __attribute__((ext_vector_type(2))) unsigned int uint2v;
typedef __attribute__((ext_vector_type(4))) unsigned int uint4v;

// ---------------- bf16 helpers ----------------
__device__ __forceinline__ float bflo(unsigned int p) { return __uint_as_float(p << 16); }
__device__ __forceinline__ float bfhi(unsigned int p) { return __uint_as_float(p & 0xffff0000u); }
__device__ __forceinline__ float bf2f(unsigned short u) { return __uint_as_float(((unsigned int)u) << 16); }
__device__ __forceinline__ unsigned int f2bfbits(float f) {
  unsigned int x = __float_as_uint(f);
  return (x + 0x7fffu + ((x >> 16) & 1u)) >> 16;
}
__device__ __forceinline__ unsigned int pack2(float lo, float hi) {
  return f2bfbits(lo) | (f2bfbits(hi) << 16);
}

// ---------------- edge_index dtype detection ----------------
__global__ void detect_idx(const int* __restrict__ idx, int* __restrict__ flag) {
  if (threadIdx.x == 0 && blockIdx.x == 0) {
    int is64 = 1;
    for (int i = 1; i < 128; i += 2) {
      if (idx[i] != 0) { is64 = 0; break; }
    }
    flag[0] = is64;
  }
}

__device__ __forceinline__ int gidx(const int* __restrict__ p, int i, int is64) {
  return is64 ? p[2 * (long long)i] : p[i];
}

// ---------------- degree + CSR row counts ----------------
__global__ void deg_cnt_kernel(const int* __restrict__ idx, const float* __restrict__ w,
                               float* __restrict__ deg_f, float* __restrict__ deg_b,
                               int* __restrict__ cnt_f, int* __restrict__ cnt_b,
                               const int* __restrict__ flag) {
  int e = blockIdx.x * 256 + threadIdx.x;
  int is64 = flag[0];
  if (e < En) {
    int s = gidx(idx, e, is64);
    int d = gidx(idx, En + e, is64);
    float we = w[e];
    atomicAdd(&deg_f[s], we);
    atomicAdd(&deg_b[d], we);
    atomicAdd(&cnt_f[d], 1);
    atomicAdd(&cnt_b[s], 1);
  }
}

// ---------------- exclusive scan ----------------
__global__ void exscan_two(const int* __restrict__ cnt_f, const int* __restrict__ cnt_b,
                           int* __restrict__ rp_f, int* __restrict__ rp_b,
                           int* __restrict__ cur_f, int* __restrict__ cur_b, int n) {
  const int* cnt = (blockIdx.x == 0) ? cnt_f : cnt_b;
  int* rp  = (blockIdx.x == 0) ? rp_f  : rp_b;
  int* cur = (blockIdx.x == 0) ? cur_f : cur_b;
  __shared__ int sh[256];
  int t = threadIdx.x;
  int running = 0;
  for (int base = 0; base < n; base += 256) {
    int v = (base + t < n) ? cnt[base + t] : 0;
    sh[t] = v;
    __syncthreads();
    for (int off = 1; off < 256; off <<= 1) {
      int x = (t >= off) ? sh[t - off] : 0;
      __syncthreads();
      sh[t] += x;
      __syncthreads();
    }
    int excl = sh[t] - v;
    if (base + t < n) { rp[base + t] = running + excl; cur[base + t] = running + excl; }
    int total = sh[255];
    __syncthreads();
    running += total;
  }
  if (t == 0) rp[n] = running;
}

// ---------------- CSR fill: packed (col, w) uint2 ----------------
__global__ void fill_csr(const int* __restrict__ idx, const float* __restrict__ w,
                         const float* __restrict__ deg_f, const float* __restrict__ deg_b,
                         int* __restrict__ cur_f, int* __restrict__ cur_b,
                         uint2v* __restrict__ cwf, uint2v* __restrict__ cwb,
                         const int* __restrict__ flag) {
  int e = blockIdx.x * 256 + threadIdx.x;
  int is64 = flag[0];
  if (e < En) {
    int s = gidx(idx, e, is64);
    int d = gidx(idx, En + e, is64);
    float we = w[e];
    int pf = atomicAdd(&cur_f[d], 1);
    uint2v ef; ef.x = (unsigned int)s; ef.y = __float_as_uint(we / deg_f[s]);
    cwf[pf] = ef;
    int pb = atomicAdd(&cur_b[s], 1);
    uint2v eb; eb.x = (unsigned int)d; eb.y = __float_as_uint(we / deg_b[d]);
    cwb[pb] = eb;
  }
}

// ---------------- weight prep: transposed bf16, W0 folded (W0-W3-W4) ----------------
__global__ void build_wt(const float* __restrict__ ru_p, const float* __restrict__ c_p,
                         unsigned short* __restrict__ Wt1, unsigned short* __restrict__ Wt2) {
  int i = blockIdx.x * 256 + threadIdx.x;
  if (i < 128 * 480) {
    int n = i / 480, k = i % 480;
    int t = k / 96, kk = k % 96;
    float v;
    if (t == 0) v = ru_p[(kk * 5 + 0) * 128 + n] - ru_p[(kk * 5 + 3) * 128 + n] - ru_p[(kk * 5 + 4) * 128 + n];
    else        v = ru_p[(kk * 5 + t) * 128 + n];
    Wt1[i] = (unsigned short)f2bfbits(v);
  }
  if (i < 64 * 480) {
    int n = i / 480, k = i % 480;
    int t = k / 96, kk = k % 96;
    float v;
    if (t == 0) v = c_p[(kk * 5 + 0) * 64 + n] - c_p[(kk * 5 + 3) * 64 + n] - c_p[(kk * 5 + 4) * 64 + n];
    else        v = c_p[(kk * 5 + t) * 64 + n];
    Wt2[i] = (unsigned short)f2bfbits(v);
  }
}

// ---------------- X0 builder ----------------
__global__ void build_x0_ru(const float* __restrict__ x, const float* __restrict__ h,
                            unsigned int* __restrict__ X0) {
  long long p = (long long)blockIdx.x * 256 + threadIdx.x;
  int node = (int)(p / WROWU);
  int rem = (int)(p % WROWU);
  int b = rem / 48;
  int ci = (rem % 48) * 2;
  float lo, hi;
  if (ci < CIN) {
    const float* s = x + ((size_t)b * Nn + node) * CIN + ci;
    lo = s[0]; hi = s[1];
  } else {
    const float* s = h + ((size_t)b * Nn + node) * COUTn + (ci - CIN);
    lo = s[0]; hi = s[1];
  }
  X0[p] = pack2(lo, hi);
}

// ---------------- XCD-sliced propagation, uint4 gathers, multi-edge waves ------
// Node rows of RU4 uint4 are split into 8 channel slices of ACT uint4.
// slice = blockIdx & 7 -> each XCD gathers only its own 3.84/2.56 MB slice
// (L2-resident; verified FETCH 627->175 MB in round 1).
// One ROW per wave; EPW = 64>>LGRP edges processed simultaneously by
// (1<<LGRP)-lane groups, each lane gathering one contiguous uint4 (16B).
// Per edge: 1/EPW gather instructions. Cross-group shfl_xor reduce at end.
// Edge loads / output stores nontemporal so the node slice owns the L2.
__device__ __forceinline__ void acc8(float* a, uint4v q, float w) {
  a[0] += w * bflo(q.x); a[1] += w * bfhi(q.x);
  a[2] += w * bflo(q.y); a[3] += w * bfhi(q.y);
  a[4] += w * bflo(q.z); a[5] += w * bfhi(q.z);
  a[6] += w * bflo(q.w); a[7] += w * bfhi(q.w);
}

template<int RU4, int ACT, int LGRP>
__device__ __forceinline__ void prop_row4(const uint4v* __restrict__ in,
                                          uint4v* __restrict__ out,
                                          const int* __restrict__ rp,
                                          const uint2v* __restrict__ cw,
                                          int row, int slice, int lane, float alpha) {
  constexpr int EPW = 64 >> LGRP;
  int g  = lane >> LGRP;
  int lg = lane & ((1 << LGRP) - 1);
  int lgc = (lg < ACT) ? lg : 0;          // clamp pad lanes onto lane 0's line
  const uint4v* __restrict__ base = in + slice * ACT + lgc;
  int jb = rp[row], je = rp[row + 1];
  int len = je - jb;

  float a[8];
  #pragma unroll
  for (int k = 0; k < 8; ++k) a[k] = 0.f;

  int i = 0;
  for (; i + 2 * EPW <= len; i += 2 * EPW) {
    uint2v e0 = __builtin_nontemporal_load(&cw[jb + i + g]);
    uint2v e1 = __builtin_nontemporal_load(&cw[jb + i + EPW + g]);
    uint4v q0 = base[(size_t)e0.x * RU4];
    uint4v q1 = base[(size_t)e1.x * RU4];
    acc8(a, q0, __uint_as_float(e0.y));
    acc8(a, q1, __uint_as_float(e1.y));
  }
  for (; i < len; i += EPW) {            // masked tail (<= 2 iterations)
    int idx = i + g;
    bool v = idx < len;
    uint2v e = __builtin_nontemporal_load(&cw[jb + (v ? idx : 0)]);
    float w = v ? __uint_as_float(e.y) : 0.f;
    unsigned int col = v ? e.x : 0u;
    uint4v q = base[(size_t)col * RU4];
    acc8(a, q, w);
  }

  #pragma unroll
  for (int k = 0; k < 8; ++k) {
    if (LGRP == 4) a[k] += __shfl_xor(a[k], 16);
    a[k] += __shfl_xor(a[k], 32);
  }

  if (lane < ACT) {
    uint4v o;
    o.x = pack2(alpha * a[0], alpha * a[1]);
    o.y = pack2(alpha * a[2], alpha * a[3]);
    o.z = pack2(alpha * a[4], alpha * a[5]);
    o.w = pack2(alpha * a[6], alpha * a[7]);
    __builtin_nontemporal_store(o, &out[(size_t)row * RU4 + slice * ACT + lane]);
  }
}

template<int RU4, int ACT, int LGRP>
__launch_bounds__(256)
__global__ void prop_dual4(const uint4v* __restrict__ in,
                           uint4v* __restrict__ outF, uint4v* __restrict__ outB,
                           const int* __restrict__ rp_f, const uint2v* __restrict__ cwf,
                           const int* __restrict__ rp_b, const uint2v* __restrict__ cwb) {
  int lane = threadIdx.x & 63;
  int wave = threadIdx.x >> 6;
  int slice = blockIdx.x & 7;
  int row = (blockIdx.x >> 3) * 4 + wave;
  prop_row4<RU4, ACT, LGRP>(in, outF, rp_f, cwf, row, slice, lane, 1.f);
  prop_row4<RU4, ACT, LGRP>(in, outB, rp_b, cwb, row, slice, lane, 1.f);
}

template<int RU4, int ACT, int LGRP>
__launch_bounds__(256)
__global__ void prop_ck4(const uint4v* __restrict__ in, uint4v* __restrict__ out,
                         const int* __restrict__ rp, const uint2v* __restrict__ cw,
                         float alpha) {
  int lane = threadIdx.x & 63;
  int wave = threadIdx.x >> 6;
  int slice = blockIdx.x & 7;
  int row = (blockIdx.x >> 3) * 4 + wave;
  prop_row4<RU4, ACT, LGRP>(in, out, rp, cw, row, slice, lane, alpha);
}

// ---------------- MFMA multi-term GEMM ----------------
// C[128 x NT] per block; 4 waves, each 32 x NT. K = nterms*96.
// Weight columns for loop term t are taken at (t0 + t)*96.
// MFMA layouts (verified): A[m=lane&15][k=quad*8+j]; B[k=quad*8+j][n=lane&15];
//                          C/D col=lane&15, row=quad*4+reg.
// MODE 0: conv1 epilogue: v=sigmoid(bias+acc); col<64 -> rh0=v*h (bf16); else U=v (bf16)
// MODE 1: outp = bias + acc (f32, batch-major)
// MODE 2: cp = outp + acc; c=tanh(tanh(cp)); u from U_in; outp = u*h + (1-u)*c
struct Msrc {
  const uint4* xs[5];
  const uint4* rh[5];
};

template<int NT, int MODE>
__launch_bounds__(256)
__global__ void gemm_mfma(Msrc g, int nterms, int t0,
                          const unsigned short* __restrict__ Wt,
                          const float* __restrict__ bias,
                          float* __restrict__ outp,
                          unsigned short* __restrict__ rh0_s,
                          unsigned short* __restrict__ U_out,
                          const unsigned short* __restrict__ U_in,
                          const float* __restrict__ hglob) {
  constexpr int NJ = NT / 16;
  __shared__ __align__(16) unsigned short As[128][104];   // 13 x 16B per row (odd -> conflict-free)
  __shared__ __align__(16) unsigned short Bs[NT][104];

  int m0 = blockIdx.x * 128;
  int tid = threadIdx.x;
  int wave = tid >> 6;
  int lane = tid & 63;
  int quad = lane >> 4;
  int lm = lane & 15;
  int wm = wave * 32;
  int nodeBase = m0 >> 4;

  f32x4 acc[2][NJ];
  #pragma unroll
  for (int i = 0; i < 2; ++i)
    #pragma unroll
    for (int j = 0; j < NJ; ++j) acc[i][j] = (f32x4){0.f, 0.f, 0.f, 0.f};

  for (int t = 0; t < nterms; ++t) {
    const uint4* xs4 = g.xs[t];
    const uint4* rh4 = g.rh[t];
    if (rh4 == nullptr) {
      const uint4* src = xs4 + (size_t)m0 * 12;
      #pragma unroll
      for (int it = 0; it < 6; ++it) {
        int q = tid + it * 256;
        uint4 v = src[q];
        int row = q / 12, slot = q % 12;
        *(uint4*)&As[row][slot * 8] = v;
      }
    } else {
      #pragma unroll
      for (int it = 0; it < 6; ++it) {
        int q = tid + it * 256;
        int row = q / 12, slot = q % 12;
        int node = nodeBase + (row >> 4);
        int b = row & 15;
        uint4 v; int ci0;
        if (slot < 4) { v = xs4[(size_t)node * 192 + b * 12 + slot]; ci0 = slot * 8; }
        else          { v = rh4[(size_t)node * 128 + b * 8 + (slot - 4)]; ci0 = 32 + (slot - 4) * 8; }
        *(uint4*)&As[row][ci0] = v;
      }
    }
    for (int q = tid; q < NT * 12; q += 256) {
      int n = q / 12, slot = q % 12;
      uint4 v = *(const uint4*)(Wt + (size_t)n * 480 + (t0 + t) * 96 + slot * 8);
      *(uint4*)&Bs[n][slot * 8] = v;
    }
    __syncthreads();

    #pragma unroll
    for (int k32 = 0; k32 < 3; ++k32) {
      int kb = k32 * 32 + quad * 8;
      short8 a0 = *(const short8*)&As[wm + lm][kb];
      short8 a1 = *(const short8*)&As[wm + 16 + lm][kb];
      #pragma unroll
      for (int j = 0; j < NJ; ++j) {
        short8 bf = *(const short8*)&Bs[j * 16 + lm][kb];
        acc[0][j] = __builtin_amdgcn_mfma_f32_16x16x32_bf16(a0, bf, acc[0][j], 0, 0, 0);
        acc[1][j] = __builtin_amdgcn_mfma_f32_16x16x32_bf16(a1, bf, acc[1][j], 0, 0, 0);
      }
    }
    __syncthreads();
  }

  #pragma unroll
  for (int i = 0; i < 2; ++i) {
    #pragma unroll
    for (int j = 0; j < NJ; ++j) {
      int col = j * 16 + lm;
      #pragma unroll
      for (int r = 0; r < 4; ++r) {
        int row = m0 + wm + i * 16 + quad * 4 + r;
        int node = row >> 4, b = row & 15;
        float v = acc[i][j][r];
        if (MODE == 0) {
          float s = 1.f / (1.f + expf(-(bias[col] + v)));
          if (col < COUTn) {
            float hv = hglob[((size_t)b * Nn + node) * COUTn + col];
            rh0_s[(size_t)row * 64 + col] = (unsigned short)f2bfbits(s * hv);
          } else {
            U_out[(size_t)row * 64 + (col - COUTn)] = (unsigned short)f2bfbits(s);
          }
        } else if (MODE == 1) {
          outp[((size_t)b * Nn + node) * COUTn + col] = bias[col] + v;
        } else {
          size_t oa = ((size_t)b * Nn + node) * COUTn + col;
          float cp = outp[oa] + v;
          float c = tanhf(tanhf(cp));
          float u = bf2f(U_in[(size_t)row * 64 + col]);
          outp[oa] = u * hglob[oa] + (1.f - u) * c;
        }
      }
    }
  }
}

// ---------------- host ----------------
extern "C" void kernel_launch(void* const* d_in, const int* in_sizes, int n_in,
                              void* d_out, int out_size, void* d_ws, size_t ws_size,
                              hipStream_t stream) {
  const float* x   = (const float*)d_in[0];
  const float* h   = (const float*)d_in[1];
  const int*   idx = (const int*)d_in[2];
  const float* ew  = (const float*)d_in[3];
  const float* ru_param = (const float*)d_in[4];
  const float* ru_bias  = (const float*)d_in[5];
  const float* c_param  = (const float*)d_in[6];
  const float* c_bias   = (const float*)d_in[7];
  float* outp = (float*)d_out;
  (void)in_sizes; (void)n_in; (void)out_size; (void)ws_size;

  char* ws = (char*)d_ws;
  size_t off = 0;
  auto alloc = [&](size_t bytes) -> char* {
    char* p = ws + off;
    off += (bytes + 255) & ~(size_t)255;
    return p;
  };

  float* deg_f = (float*)alloc(40960);
  float* deg_b = (float*)alloc(40960);
  int*   cnt_f = (int*)alloc(40960);
  int*   cnt_b = (int*)alloc(40960);
  int*   rp_f  = (int*)alloc((Nn + 1) * sizeof(int));
  int*   rp_b  = (int*)alloc((Nn + 1) * sizeof(int));
  int*   cur_f = (int*)alloc(Nn * sizeof(int));
  int*   cur_b = (int*)alloc(Nn * sizeof(int));
  int*   flag  = (int*)alloc(256);
  uint2v* cwf  = (uint2v*)alloc((size_t)En * 8);
  uint2v* cwb  = (uint2v*)alloc((size_t)En * 8);
  unsigned short* Wt1 = (unsigned short*)alloc(128 * 480 * 2);
  unsigned short* Wt2 = (unsigned short*)alloc(64 * 480 * 2);

  unsigned int* A0   = (unsigned int*)alloc((size_t)Nn * WROWU * 4);
  unsigned int* T1f  = (unsigned int*)alloc((size_t)Nn * WROWU * 4);
  unsigned int* T1b  = (unsigned int*)alloc((size_t)Nn * WROWU * 4);
  unsigned int* T2f  = (unsigned int*)alloc((size_t)Nn * WROWU * 4);
  unsigned int* T2b  = (unsigned int*)alloc((size_t)Nn * WROWU * 4);
  unsigned int* rh0  = (unsigned int*)alloc((size_t)Nn * RHU * 4);
  unsigned int* rh1f = (unsigned int*)alloc((size_t)Nn * RHU * 4);
  unsigned int* rh1b = (unsigned int*)alloc((size_t)Nn * RHU * 4);
  unsigned int* Ubuf = (unsigned int*)alloc((size_t)Nn * RHU * 4);
  // ~241 MB total

  hipMemsetAsync(ws, 0, 4 * 40960, stream);
  detect_idx<<<1, 64, 0, stream>>>(idx, flag);
  deg_cnt_kernel<<<En / 256, 256, 0, stream>>>(idx, ew, deg_f, deg_b, cnt_f, cnt_b, flag);
  exscan_two<<<2, 256, 0, stream>>>(cnt_f, cnt_b, rp_f, rp_b, cur_f, cur_b, Nn);
  fill_csr<<<En / 256, 256, 0, stream>>>(idx, ew, deg_f, deg_b, cur_f, cur_b,
                                         cwf, cwb, flag);
  build_wt<<<240, 256, 0, stream>>>(ru_param, c_param, Wt1, Wt2);

  const int gBuild = Nn * WROWU / 256;
  const int gP = (Nn / 4) * 8;   // 4 rows/block (1 per wave) x 8 XCD slices

  // ===== conv1 diffusion (rows of 192 uint4, slices of 24 uint4, 2 edges/wave) =====
  build_x0_ru<<<gBuild, 256, 0, stream>>>(x, h, A0);
  prop_dual4<192, 24, 5><<<gP, 256, 0, stream>>>(
      (const uint4v*)A0, (uint4v*)T1f, (uint4v*)T1b, rp_f, cwf, rp_b, cwb);
  prop_ck4<192, 24, 5><<<gP, 256, 0, stream>>>(
      (const uint4v*)T1f, (uint4v*)T2f, rp_f, cwf, 2.f);
  prop_ck4<192, 24, 5><<<gP, 256, 0, stream>>>(
      (const uint4v*)T1b, (uint4v*)T2b, rp_b, cwb, 2.f);

  // ===== conv1 projection: one MFMA GEMM K=480, fused sigmoid + r*h + u-store =====
  Msrc g1;
  g1.xs[0] = (const uint4*)A0;  g1.rh[0] = nullptr;
  g1.xs[1] = (const uint4*)T1f; g1.rh[1] = nullptr;
  g1.xs[2] = (const uint4*)T1b; g1.rh[2] = nullptr;
  g1.xs[3] = (const uint4*)T2f; g1.rh[3] = nullptr;
  g1.xs[4] = (const uint4*)T2b; g1.rh[4] = nullptr;
  gemm_mfma<128, 0><<<MROWS / 128, 256, 0, stream>>>(
      g1, 5, 0, Wt1, ru_bias, nullptr,
      (unsigned short*)rh0, (unsigned short*)Ubuf, nullptr, h);

  // ===== conv2 diffusion on rh (rows of 128 uint4, slices of 16 uint4, 4 edges/wave) =====
  prop_dual4<128, 16, 4><<<gP, 256, 0, stream>>>(
      (const uint4v*)rh0, (uint4v*)rh1f, (uint4v*)rh1b, rp_f, cwf, rp_b, cwb);

  // conv2 pass A: terms 0,1,2 (weight base t0=0)
  Msrc g2a;
  g2a.xs[0] = (const uint4*)A0;  g2a.rh[0] = (const uint4*)rh0;
  g2a.xs[1] = (const uint4*)T1f; g2a.rh[1] = (const uint4*)rh1f;
  g2a.xs[2] = (const uint4*)T1b; g2a.rh[2] = (const uint4*)rh1b;
  g2a.xs[3] = nullptr; g2a.rh[3] = nullptr;
  g2a.xs[4] = nullptr; g2a.rh[4] = nullptr;
  gemm_mfma<64, 1><<<MROWS / 128, 256, 0, stream>>>(
      g2a, 3, 0, Wt2, c_bias, outp, nullptr, nullptr, nullptr, nullptr);

  // rh second-order terms (reuse rh0/rh1f storage after pass A consumed them)
  prop_ck4<128, 16, 4><<<gP, 256, 0, stream>>>(
      (const uint4v*)rh1f, (uint4v*)rh0, rp_f, cwf, 2.f);   // rh2f
  prop_ck4<128, 16, 4><<<gP, 256, 0, stream>>>(
      (const uint4v*)rh1b, (uint4v*)rh1f, rp_b, cwb, 2.f);  // rh2b

  // conv2 pass B: terms 3,4 (weight base t0=3) + fused GRU final
  Msrc g2b;
  g2b.xs[0] = (const uint4*)T2f; g2b.rh[0] = (const uint4*)rh0;
  g2b.xs[1] = (const uint4*)T2b; g2b.rh[1] = (const uint4*)rh1f;
  g2b.xs[2] = nullptr; g2b.rh[2] = nullptr;
  g2b.xs[3] = nullptr; g2b.rh[3] = nullptr;
  g2b.xs[4] = nullptr; g2b.rh[4] = nullptr;
  gemm_mfma<64, 2><<<MROWS / 128, 256, 0, stream>>>(
      g2b, 2, 3, Wt2, c_bias, outp, nullptr, nullptr,
      (const unsigned short*)Ubuf, h);
}